// Round 1
// baseline (77.708 us; speedup 1.0000x reference)
//
#include <hip/hip_runtime.h>
#include <math.h>

// GCDD layer fused kernel.
// out = u + div( phi(G)*ux, phi(G)*uy ), all convs = 3x3 Sobel cross-correlation,
// zero padding applied at EVERY conv stage (so intermediates are zero outside domain).

#define TILE 32
#define HALO 3
#define SU (TILE + 2*HALO)   // 38: u tile with halo 3
#define SD (TILE + 4)        // 36: first derivatives, halo 2
#define SP (TILE + 2)        // 34: P/Q, halo 1
#define LDSW 40              // padded LDS row stride (floats)

__global__ __launch_bounds__(256) void gcdd_fused(
    const float* __restrict__ u, float* __restrict__ out, int H, int W)
{
    __shared__ float su [SU][LDSW];
    __shared__ float sux[SD][LDSW];
    __shared__ float suy[SD][LDSW];
    __shared__ float sP [SP][LDSW];
    __shared__ float sQ [SP][LDSW];

    const int tid = threadIdx.x;
    const int tx0 = blockIdx.x * TILE;
    const int ty0 = blockIdx.y * TILE;
    const long chan = blockIdx.z;
    const float* __restrict__ uc = u + chan * (long)H * W;
    float* __restrict__ oc = out + chan * (long)H * W;

    // ---- Stage 1: load u tile + halo 3 (zero padded) ----
    for (int i = tid; i < SU * SU; i += 256) {
        int ly = i / SU, lx = i - ly * SU;
        int gy = ty0 + ly - HALO, gx = tx0 + lx - HALO;
        float v = 0.f;
        if (gy >= 0 && gy < H && gx >= 0 && gx < W)
            v = uc[(long)gy * W + gx];
        su[ly][lx] = v;
    }
    __syncthreads();

    // ---- Stage 2: ux, uy on halo-2 region; zero outside domain ----
    for (int i = tid; i < SD * SD; i += 256) {
        int ly = i / SD, lx = i - ly * SD;
        int gy = ty0 + ly - 2, gx = tx0 + lx - 2;
        float vx = 0.f, vy = 0.f;
        if (gy >= 0 && gy < H && gx >= 0 && gx < W) {
            int sy = ly + 1, sx = lx + 1;  // index into su
            float a = su[sy-1][sx-1], b = su[sy-1][sx], c = su[sy-1][sx+1];
            float d = su[sy  ][sx-1],                   e = su[sy  ][sx+1];
            float f = su[sy+1][sx-1], g = su[sy+1][sx], h = su[sy+1][sx+1];
            // SOBEL_X = [[-1,0,1],[-2,0,2],[-1,0,1]] (cross-correlation)
            vx = (c - a) + 2.f*(e - d) + (h - f);
            // SOBEL_Y = [[-1,-2,-1],[0,0,0],[1,2,1]]
            vy = (f + 2.f*g + h) - (a + 2.f*b + c);
        }
        sux[ly][lx] = vx;
        suy[ly][lx] = vy;
    }
    __syncthreads();

    // ---- Stage 3: second derivatives -> G -> phi -> P,Q on halo-1 region ----
    for (int i = tid; i < SP * SP; i += 256) {
        int ly = i / SP, lx = i - ly * SP;
        int gy = ty0 + ly - 1, gx = tx0 + lx - 1;
        float p = 0.f, q = 0.f;
        if (gy >= 0 && gy < H && gx >= 0 && gx < W) {
            int sy = ly + 1, sx = lx + 1;  // index into sux/suy
            float xa = sux[sy-1][sx-1], xb = sux[sy-1][sx], xc = sux[sy-1][sx+1];
            float xd = sux[sy  ][sx-1], xm = sux[sy  ][sx], xe = sux[sy  ][sx+1];
            float xf = sux[sy+1][sx-1], xg = sux[sy+1][sx], xh = sux[sy+1][sx+1];
            float uxx = (xc - xa) + 2.f*(xe - xd) + (xh - xf);
            float uxy = (xf + 2.f*xg + xh) - (xa + 2.f*xb + xc);
            float ya = suy[sy-1][sx-1], yb = suy[sy-1][sx], yc = suy[sy-1][sx+1];
            float ym = suy[sy  ][sx];
            float yf = suy[sy+1][sx-1], yg = suy[sy+1][sx], yh = suy[sy+1][sx+1];
            float uyy = (yf + 2.f*yg + yh) - (ya + 2.f*yb + yc);
            float den = 1.f + xm*xm + ym*ym;
            den = den * den;
            float G = (uxx*uyy - uxy*uxy) / (den + 1e-6f);
            float phi = __expf(-fabsf(G));
            p = phi * xm;
            q = phi * ym;
        }
        sP[ly][lx] = p;
        sQ[ly][lx] = q;
    }
    __syncthreads();

    // ---- Stage 4: divergence + residual output (interior 32x32, H,W multiples of TILE) ----
    for (int i = tid; i < TILE * TILE; i += 256) {
        int ly = i / TILE, lx = i - ly * TILE;
        int gy = ty0 + ly, gx = tx0 + lx;
        int sy = ly + 1, sx = lx + 1;  // index into sP/sQ
        float divx = (sP[sy-1][sx+1] - sP[sy-1][sx-1])
                   + 2.f*(sP[sy][sx+1] - sP[sy][sx-1])
                   + (sP[sy+1][sx+1] - sP[sy+1][sx-1]);
        float divy = (sQ[sy+1][sx-1] + 2.f*sQ[sy+1][sx] + sQ[sy+1][sx+1])
                   - (sQ[sy-1][sx-1] + 2.f*sQ[sy-1][sx] + sQ[sy-1][sx+1]);
        oc[(long)gy * W + gx] = su[ly + HALO][lx + HALO] + divx + divy;
    }
}

extern "C" void kernel_launch(void* const* d_in, const int* in_sizes, int n_in,
                              void* d_out, int out_size, void* d_ws, size_t ws_size,
                              hipStream_t stream) {
    const float* u = (const float*)d_in[0];
    // theta (d_in[1]) is unused in the reference forward output.
    float* out = (float*)d_out;

    const int H = 512, W = 512;
    const int channels = in_sizes[0] / (H * W);  // B*C = 48

    dim3 grid(W / TILE, H / TILE, channels);
    dim3 block(256);
    gcdd_fused<<<grid, block, 0, stream>>>(u, out, H, W);
}